// Round 2
// baseline (12849.452 us; speedup 1.0000x reference)
//
#include <hip/hip_runtime.h>
#include <math.h>

#define NN   29040
#define NLAT 121
#define NLON 240
#define HD   128
#define LVN  11
#define EE   464640
#define NPB  16          // nodes per block in edge kernel

// ---------------- CSR build ----------------
__global__ __launch_bounds__(256)
void hist_kernel(const int* __restrict__ eidx, int* __restrict__ cnt)
{
    int e = blockIdx.x * 256 + threadIdx.x;
    if (e < EE) atomicAdd(&cnt[eidx[e]], 1);
}

__global__ __launch_bounds__(1024)
void scan_kernel(const int* __restrict__ cnt, int* __restrict__ off)
{
    __shared__ int part[1024];
    const int tid = threadIdx.x;
    const int CH = 29;                       // 1024*29 >= 29040
    int lo = tid * CH, hi = min(lo + CH, NN);
    int s = 0;
    for (int i = lo; i < hi; ++i) s += cnt[i];
    part[tid] = s;
    __syncthreads();
    for (int d = 1; d < 1024; d <<= 1) {
        int v = (tid >= d) ? part[tid - d] : 0;
        __syncthreads();
        part[tid] += v;
        __syncthreads();
    }
    int run = (tid == 0) ? 0 : part[tid - 1];
    for (int i = lo; i < hi; ++i) { off[i] = run; run += cnt[i]; }
    if (tid == 1023) off[NN] = run;          // == EE
}

__global__ __launch_bounds__(256)
void scatter_kernel(const int* __restrict__ eidx, const int* __restrict__ off,
                    int* __restrict__ cur, int* __restrict__ csr)
{
    int e = blockIdx.x * 256 + threadIdx.x;
    if (e >= EE) return;
    int row = eidx[e];
    int p = atomicAdd(&cur[row], 1);
    csr[off[row] + p] = e;
}

// ---------------- edge kernel: CSR-ordered, LDS aggregation ----------------
__global__ __launch_bounds__(256, 1)
void edge_csr_kernel(const float* __restrict__ h,
                     const float* __restrict__ u,
                     const float* __restrict__ v,
                     const float* __restrict__ ea,
                     const float* __restrict__ We1, const float* __restrict__ be1,
                     const float* __restrict__ We2, const float* __restrict__ be2,
                     const float* __restrict__ Wc1, const float* __restrict__ bc1,
                     const float* __restrict__ Wcl,
                     const int* __restrict__ eidx,
                     const int* __restrict__ csr,
                     const int* __restrict__ off,
                     float* __restrict__ agg,    // [NN,HD]
                     float* __restrict__ aggu,   // [NN,LVN] final
                     float* __restrict__ aggv)   // [NN,LVN] final
{
    __shared__ float lagg[NPB * 129];
    __shared__ float lu[NPB * 12];
    __shared__ float lv[NPB * 12];

    const int tid = threadIdx.x;
    const int nb = blockIdx.x * NPB;

    for (int i = tid; i < NPB * 129; i += 256) lagg[i] = 0.f;
    for (int i = tid; i < NPB * 12; i += 256) { lu[i] = 0.f; lv[i] = 0.f; }
    __syncthreads();

    const int e0 = off[nb];
    const int e1 = off[nb + NPB];

    for (int idx = e0 + tid; idx < e1; idx += 256) {
        const int e   = csr[idx];
        const int row = eidx[e];
        const int col = eidx[EE + e];
        const int lrow = row - nb;

        // ---- coord2radial ----
        float wd[33];
        float ucn = 0.f, vcn = 0.f;
#pragma unroll
        for (int l = 0; l < LVN; ++l) {
            float uc = u[col * LVN + l], vc = v[col * LVN + l];
            float ur = u[row * LVN + l], vr = v[row * LVN + l];
            float cs = sqrtf(uc * uc + vc * vc);
            float rs = sqrtf(ur * ur + vr * vr);
            wd[l]      = (uc * ur + vc * vr) / (cs * rs);
            wd[11 + l] = cs;
            wd[22 + l] = rs;
            ucn += uc * uc;
            vcn += vc * vc;
        }
        const float radu = sqrtf(ucn), radv = sqrtf(vcn);

        // ---- edge MLP layer 1 ----
        float acc[HD];
#pragma unroll
        for (int j = 0; j < HD; ++j) acc[j] = be1[j];
#pragma unroll
        for (int k = 0; k < 33; ++k) {
            float x = wd[k];
            const float* w = We1 + (size_t)(256 + k) * HD;
#pragma unroll
            for (int j = 0; j < HD; ++j) acc[j] = fmaf(x, w[j], acc[j]);
        }
        {
            float x = ea[e];
            const float* w = We1 + (size_t)289 * HD;
#pragma unroll
            for (int j = 0; j < HD; ++j) acc[j] = fmaf(x, w[j], acc[j]);
        }
        for (int k = 0; k < HD; ++k) {
            float x = h[(size_t)row * HD + k];
            const float* w = We1 + (size_t)k * HD;
#pragma unroll
            for (int j = 0; j < HD; ++j) acc[j] = fmaf(x, w[j], acc[j]);
        }
        for (int k = 0; k < HD; ++k) {
            float x = h[(size_t)col * HD + k];
            const float* w = We1 + (size_t)(HD + k) * HD;
#pragma unroll
            for (int j = 0; j < HD; ++j) acc[j] = fmaf(x, w[j], acc[j]);
        }
#pragma unroll
        for (int j = 0; j < HD; ++j) acc[j] = fmaxf(acc[j], 0.f);

        // ---- edge MLP layer 2 ----
        float ef[HD];
#pragma unroll
        for (int j = 0; j < HD; ++j) ef[j] = be2[j];
        for (int k = 0; k < HD; ++k) {
            float x = acc[k];
            const float* w = We2 + (size_t)k * HD;
#pragma unroll
            for (int j = 0; j < HD; ++j) ef[j] = fmaf(x, w[j], ef[j]);
        }
#pragma unroll
        for (int j = 0; j < HD; ++j) ef[j] = fmaxf(ef[j], 0.f);

        // ---- scatter to LDS ----
#pragma unroll
        for (int j = 0; j < HD; ++j) atomicAdd(&lagg[lrow * 129 + j], ef[j]);

        // ---- coord MLP ----
#pragma unroll
        for (int j = 0; j < HD; ++j) acc[j] = bc1[j];
        for (int k = 0; k < HD; ++k) {
            float x = ef[k];
            const float* w = Wc1 + (size_t)k * HD;
#pragma unroll
            for (int j = 0; j < HD; ++j) acc[j] = fmaf(x, w[j], acc[j]);
        }
#pragma unroll
        for (int j = 0; j < HD; ++j) acc[j] = fmaxf(acc[j], 0.f);

        float o22[22];
#pragma unroll
        for (int j = 0; j < 22; ++j) o22[j] = 0.f;
        for (int k = 0; k < HD; ++k) {
            float x = acc[k];
            const float* w = Wcl + (size_t)k * 22;
#pragma unroll
            for (int j = 0; j < 22; ++j) o22[j] = fmaf(x, w[j], o22[j]);
        }
#pragma unroll
        for (int l = 0; l < LVN; ++l) {
            atomicAdd(&lu[lrow * 12 + l], o22[l] * radu);
            atomicAdd(&lv[lrow * 12 + l], o22[11 + l] * radv);
        }
    }
    __syncthreads();

    // ---- write agg (raw) ----
    for (int i = tid; i < NPB * HD; i += 256) {
        int ln = i >> 7, j = i & 127;
        agg[(size_t)(nb + ln) * HD + j] = lagg[ln * 129 + j];
    }
    // ---- write finalized wind ----
    for (int i = tid; i < NPB * LVN; i += 256) {
        int ln = i / LVN, l = i % LVN;
        int n = nb + ln;
        float c = fmaxf((float)(off[n + 1] - off[n]), 1.f);
        float xu = lu[ln * 12 + l] / c;
        float xv = lv[ln * 12 + l] / c;
        xu = fminf(fmaxf(xu, -100.f), 100.f);
        xv = fminf(fmaxf(xv, -100.f), 100.f);
        aggu[(size_t)n * LVN + l] = xu;
        aggv[(size_t)n * LVN + l] = xv;
    }
}

// ---------------- lat-band mean over longitude ----------------
__global__ __launch_bounds__(256)
void lat_kernel(const float* __restrict__ agg, float* __restrict__ lat)
{
    int t = blockIdx.x * 256 + threadIdx.x;
    if (t >= NLAT * HD) return;
    int i = t / HD, j = t % HD;
    float s = 0.f;
    for (int lon = 0; lon < NLON; ++lon)
        s += agg[((size_t)i * NLON + lon) * HD + j];
    lat[t] = s * (1.0f / NLON);
}

// ---------------- node kernel: MLP + residual ----------------
__global__ __launch_bounds__(256, 1)
void node_kernel(const float* __restrict__ h,
                 const float* __restrict__ Wn1, const float* __restrict__ bn1,
                 const float* __restrict__ Wn2, const float* __restrict__ bn2,
                 const float* __restrict__ lat,
                 float* __restrict__ hout)   // in: agg, out: h_out
{
    int n = blockIdx.x * 256 + threadIdx.x;
    if (n >= NN) return;
    int li = n / NLON;

    float acc[HD];
#pragma unroll
    for (int j = 0; j < HD; ++j) acc[j] = bn1[j];
    for (int k = 0; k < HD; ++k) {
        float x = h[(size_t)n * HD + k];
        const float* w = Wn1 + (size_t)k * HD;
#pragma unroll
        for (int j = 0; j < HD; ++j) acc[j] = fmaf(x, w[j], acc[j]);
    }
    for (int k = 0; k < HD; ++k) {
        float x = hout[(size_t)n * HD + k];
        const float* w = Wn1 + (size_t)(HD + k) * HD;
#pragma unroll
        for (int j = 0; j < HD; ++j) acc[j] = fmaf(x, w[j], acc[j]);
    }
    for (int k = 0; k < HD; ++k) {
        float x = lat[(size_t)li * HD + k];
        const float* w = Wn1 + (size_t)(2 * HD + k) * HD;
#pragma unroll
        for (int j = 0; j < HD; ++j) acc[j] = fmaf(x, w[j], acc[j]);
    }
#pragma unroll
    for (int j = 0; j < HD; ++j) acc[j] = fmaxf(acc[j], 0.f);

    float o[HD];
#pragma unroll
    for (int j = 0; j < HD; ++j) o[j] = bn2[j];
    for (int k = 0; k < HD; ++k) {
        float x = acc[k];
        const float* w = Wn2 + (size_t)k * HD;
#pragma unroll
        for (int j = 0; j < HD; ++j) o[j] = fmaf(x, w[j], o[j]);
    }
#pragma unroll
    for (int j = 0; j < HD; ++j)
        hout[(size_t)n * HD + j] = o[j] + h[(size_t)n * HD + j];
}

extern "C" void kernel_launch(void* const* d_in, const int* in_sizes, int n_in,
                              void* d_out, int out_size, void* d_ws, size_t ws_size,
                              hipStream_t stream)
{
    const float* h   = (const float*)d_in[0];
    const float* u   = (const float*)d_in[1];
    const float* v   = (const float*)d_in[2];
    const float* ea  = (const float*)d_in[3];
    const float* We1 = (const float*)d_in[4];
    const float* be1 = (const float*)d_in[5];
    const float* We2 = (const float*)d_in[6];
    const float* be2 = (const float*)d_in[7];
    const float* Wn1 = (const float*)d_in[8];
    const float* bn1 = (const float*)d_in[9];
    const float* Wn2 = (const float*)d_in[10];
    const float* bn2 = (const float*)d_in[11];
    const float* Wc1 = (const float*)d_in[12];
    const float* bc1 = (const float*)d_in[13];
    const float* Wcl = (const float*)d_in[14];
    const int*   eidx = (const int*)d_in[15];

    float* out  = (float*)d_out;
    float* agg  = out;                       // [NN,HD]: agg accum, then h_out
    float* aggu = out + (size_t)NN * HD;     // [NN,LVN]
    float* aggv = aggu + (size_t)NN * LVN;   // [NN,LVN]

    int* cnt = (int*)d_ws;                   // [NN]
    int* cur = cnt + NN;                     // [NN]
    int* off = cur + NN;                     // [NN+1]
    int* csr = off + (NN + 1);               // [EE]
    float* lat = (float*)(csr + EE);         // [NLAT*HD]

    hipMemsetAsync(cnt, 0, (size_t)NN * sizeof(int), stream);
    hipMemsetAsync(cur, 0, (size_t)NN * sizeof(int), stream);

    hist_kernel<<<EE / 256, 256, 0, stream>>>(eidx, cnt);
    scan_kernel<<<1, 1024, 0, stream>>>(cnt, off);
    scatter_kernel<<<EE / 256, 256, 0, stream>>>(eidx, off, cur, csr);

    edge_csr_kernel<<<NN / NPB, 256, 0, stream>>>(h, u, v, ea,
                                                  We1, be1, We2, be2,
                                                  Wc1, bc1, Wcl,
                                                  eidx, csr, off,
                                                  agg, aggu, aggv);

    lat_kernel<<<(NLAT * HD + 255) / 256, 256, 0, stream>>>(agg, lat);

    node_kernel<<<(NN + 255) / 256, 256, 0, stream>>>(h, Wn1, bn1, Wn2, bn2,
                                                      lat, agg);
}

// Round 3
// 552.279 us; speedup vs baseline: 23.2662x; 23.2662x over previous
//
#include <hip/hip_runtime.h>
#include <math.h>

#define NN   29040
#define NLAT 121
#define NLON 240
#define HD   128
#define LVN  11
#define EE   464640

typedef __attribute__((ext_vector_type(8))) short short8;
typedef __attribute__((ext_vector_type(4))) float f4;

// packed-weight offsets (in shorts) inside wp buffer
#define OFF_WE1 0          // 10 kf x 8 nf  = 80 frags
#define OFF_WE2 40960      // 4 x 8 = 32
#define OFF_WC1 57344      // 4 x 8 = 32
#define OFF_WCL 73728      // 4 x 2 = 8
#define OFF_WN1 77824      // 12 x 8 = 96
#define OFF_WN2 126976     // 4 x 8 = 32
#define WP_SHORTS 143360

__device__ inline unsigned short f2b(float x) {
    union { float f; unsigned u; } v; v.f = x;
    unsigned r = v.u + 0x7FFFu + ((v.u >> 16) & 1u);
    return (unsigned short)(r >> 16);
}
__device__ inline float b2f(unsigned short b) {
    union { unsigned u; float f; } v; v.u = ((unsigned)b) << 16;
    return v.f;
}

// ---------------- CSR build (unchanged, proven) ----------------
__global__ __launch_bounds__(256)
void hist_kernel(const int* __restrict__ eidx, int* __restrict__ cnt)
{
    int e = blockIdx.x * 256 + threadIdx.x;
    if (e < EE) atomicAdd(&cnt[eidx[e]], 1);
}

__global__ __launch_bounds__(1024)
void scan_kernel(const int* __restrict__ cnt, int* __restrict__ off)
{
    __shared__ int part[1024];
    const int tid = threadIdx.x;
    const int CH = 29;
    int lo = tid * CH, hi = min(lo + CH, NN);
    int s = 0;
    for (int i = lo; i < hi; ++i) s += cnt[i];
    part[tid] = s;
    __syncthreads();
    for (int d = 1; d < 1024; d <<= 1) {
        int vv = (tid >= d) ? part[tid - d] : 0;
        __syncthreads();
        part[tid] += vv;
        __syncthreads();
    }
    int run = (tid == 0) ? 0 : part[tid - 1];
    for (int i = lo; i < hi; ++i) { off[i] = run; run += cnt[i]; }
    if (tid == 1023) off[NN] = run;
}

__global__ __launch_bounds__(256)
void scatter_kernel(const int* __restrict__ eidx, const int* __restrict__ off,
                    int* __restrict__ cur, int* __restrict__ csr)
{
    int e = blockIdx.x * 256 + threadIdx.x;
    if (e >= EE) return;
    int row = eidx[e];
    int p = atomicAdd(&cur[row], 1);
    csr[off[row] + p] = e;
}

// ---------------- weight pack: f32 [K][N] -> bf16 MFMA fragment order ----------------
// frag f = kf*NFW + nf; element: lane l, i -> (k = kf*32 + 8*(l>>4) + i, n = nf*16 + (l&15))
// stored at wp[base + f*512 + l*8 + i]
__global__ __launch_bounds__(64)
void prep_kernel(const float* __restrict__ We1, const float* __restrict__ We2,
                 const float* __restrict__ Wc1, const float* __restrict__ Wcl,
                 const float* __restrict__ Wn1, const float* __restrict__ Wn2,
                 short* __restrict__ wp)
{
    const int b = blockIdx.x, l = threadIdx.x;
    int kind, f, base;
    if (b < 80)       { kind = 0; f = b;       base = OFF_WE1; }
    else if (b < 112) { kind = 1; f = b - 80;  base = OFF_WE2; }
    else if (b < 144) { kind = 2; f = b - 112; base = OFF_WC1; }
    else if (b < 152) { kind = 3; f = b - 144; base = OFF_WCL; }
    else if (b < 248) { kind = 4; f = b - 152; base = OFF_WN1; }
    else              { kind = 5; f = b - 248; base = OFF_WN2; }
    const int nfw = (kind == 3) ? 2 : 8;
    const int kf = f / nfw, nf = f % nfw;
    short* dst = wp + base + (size_t)f * 512 + l * 8;
    for (int i = 0; i < 8; ++i) {
        int k = kf * 32 + ((l >> 4) << 3) + i;
        int n = nf * 16 + (l & 15);
        float val = 0.f;
        if (kind == 0) {
            // A-col c -> We1 row: c<33: wd -> 256+c ; c==33: ea -> 289 ; c<64: pad ; else h -> c-64
            int r = (k < 33) ? (256 + k) : (k == 33 ? 289 : (k < 64 ? -1 : k - 64));
            if (r >= 0) val = We1[r * HD + n];
        } else if (kind == 1) val = We2[k * HD + n];
        else if (kind == 2)  val = Wc1[k * HD + n];
        else if (kind == 3)  { if (n < 22) val = Wcl[k * 22 + n]; }
        else if (kind == 4)  val = Wn1[k * HD + n];
        else                 val = Wn2[k * HD + n];
        dst[i] = (short)f2b(val);
    }
}

// ---------------- MFMA layer: C[128][16*NF] = A[128][KF*32] @ Wp + bias ----------------
// A in LDS, row stride rs bytes, XOR-swizzled (byte ^= (row&7)<<4 on bits 4-6).
// B fragments read directly from global packed wp (L1-cached, shared by all waves).
template<int KF, int NF>
__device__ inline void layer_gemm(const short* At, int rs, const short* Wp,
                                  const float* bias, f4* acc, int w, int lane)
{
    const int m = 16 * w + (lane & 15);
    const char* arow = (const char*)At + m * rs;
    const int sw = (m & 7) << 4;
    const int kb = (lane >> 4) << 4;   // k-block byte offset within row
#pragma unroll
    for (int nf = 0; nf < NF; ++nf) {
        float bv = bias ? bias[nf * 16 + (lane & 15)] : 0.f;
        acc[nf] = (f4){bv, bv, bv, bv};
    }
    for (int kf = 0; kf < KF; ++kf) {
        short8 a = *(const short8*)(arow + ((kf * 64 + kb) ^ sw));
        const short8* wr = (const short8*)(Wp + (size_t)kf * NF * 512) + lane;
#pragma unroll
        for (int nf = 0; nf < NF; ++nf) {
            short8 bfr = wr[nf * 64];
            acc[nf] = __builtin_amdgcn_mfma_f32_16x16x32_bf16(a, bfr, acc[nf], 0, 0, 0);
        }
    }
}

// store C frags (relu) as bf16 tile, row stride rs bytes, swizzled
template<int NF>
__device__ inline void store_tile(short* tile, int rs, const f4* acc, int w, int lane)
{
    const int rb = 16 * w + ((lane >> 4) << 2);
    const int cb = (lane & 15) * 2;
#pragma unroll
    for (int nf = 0; nf < NF; ++nf)
#pragma unroll
        for (int r = 0; r < 4; ++r) {
            int row = rb + r;
            float vv = fmaxf(acc[nf][r], 0.f);
            *(short*)((char*)tile + row * rs + ((cb + nf * 32) ^ ((row & 7) << 4))) = (short)f2b(vv);
        }
}

// ---------------- edge kernel ----------------
__global__ __launch_bounds__(512, 1)
void edge_mfma(const float* __restrict__ h, const float* __restrict__ u,
               const float* __restrict__ v, const float* __restrict__ ea,
               const float* __restrict__ be1, const float* __restrict__ be2,
               const float* __restrict__ bc1,
               const short* __restrict__ wp,
               const int* __restrict__ eidx, const int* __restrict__ csr,
               float* __restrict__ agg, float* __restrict__ aggu,
               float* __restrict__ aggv)
{
    __shared__ short Ain[128 * 320];   // 80 KB: A (640B rows); later EF tile (256B rows) + O22 f32
    __shared__ short T1[128 * 128];    // 32 KB: Y1 then C1 (256B rows)
    __shared__ int   rows_s[128];
    __shared__ int   cols_s[128];
    __shared__ float ea_s[128], radu_s[128], radv_s[128];

    const int tid = threadIdx.x, lane = tid & 63, w = tid >> 6;
    const int e0 = blockIdx.x * 128;

    if (tid < 128) {
        int e = csr[e0 + tid];
        rows_s[tid] = eidx[e];
        cols_s[tid] = eidx[EE + e];
        ea_s[tid]   = ea[e];
    }
    __syncthreads();

    // ---- gather: wd(33)+ea(1)+pad -> cols 0..63 ; h[row] -> 64..191 ; h[col] -> 192..319
    {
        const int m = tid >> 2, q = tid & 3;
        const int row = rows_s[m], col = cols_s[m];
        short* arow = Ain + m * 320;
        const int sw = (m & 7) << 4;
        float ucn = 0.f, vcn = 0.f;
        for (int l = q; l < LVN; l += 4) {
            float uc = u[col * LVN + l], vc = v[col * LVN + l];
            float ur = u[row * LVN + l], vr = v[row * LVN + l];
            float cs = sqrtf(uc * uc + vc * vc), rsd = sqrtf(ur * ur + vr * vr);
            float rd = (uc * ur + vc * vr) / (cs * rsd);
            *(short*)((char*)arow + ((2 * l) ^ sw))        = (short)f2b(rd);
            *(short*)((char*)arow + ((2 * (11 + l)) ^ sw)) = (short)f2b(cs);
            *(short*)((char*)arow + ((2 * (22 + l)) ^ sw)) = (short)f2b(rsd);
            ucn += uc * uc; vcn += vc * vc;
        }
        ucn += __shfl_xor(ucn, 1); ucn += __shfl_xor(ucn, 2);
        vcn += __shfl_xor(vcn, 1); vcn += __shfl_xor(vcn, 2);
        if (q == 0) { radu_s[m] = sqrtf(ucn); radv_s[m] = sqrtf(vcn); }
        if (q == 3) *(short*)((char*)arow + ((2 * 33) ^ sw)) = (short)f2b(ea_s[m]);
#pragma unroll
        for (int j = 0; j < 8; ++j) {
            int c = 34 + q * 8 + j;
            if (c < 64) *(short*)((char*)arow + ((2 * c) ^ sw)) = 0;
        }
        for (int part = 0; part < 2; ++part) {
            const float* hp = h + (size_t)(part ? col : row) * HD + q * 32;
            const int bb = (part ? 384 : 128) + q * 64;
#pragma unroll
            for (int k2 = 0; k2 < 4; ++k2) {
                short8 pk;
                const float* s = hp + 8 * k2;
#pragma unroll
                for (int j = 0; j < 8; ++j) pk[j] = (short)f2b(s[j]);
                *(short8*)((char*)arow + ((bb + 16 * k2) ^ sw)) = pk;
            }
        }
    }
    __syncthreads();

    f4 acc[8];
    // edge MLP layer 1
    layer_gemm<10, 8>(Ain, 640, wp + OFF_WE1, be1, acc, w, lane);
    store_tile<8>(T1, 256, acc, w, lane);
    __syncthreads();
    // edge MLP layer 2 -> EF (into Ain, 256B rows)
    layer_gemm<4, 8>(T1, 256, wp + OFF_WE2, be2, acc, w, lane);
    store_tile<8>(Ain, 256, acc, w, lane);
    __syncthreads();

    // ---- agg: segmented reduce over sorted rows, coalesced atomics
    {
        const int n = tid & 127, q = tid >> 7;
        const int m0 = q * 32;
        int cur = rows_s[m0]; float s = 0.f;
        for (int m = m0; m < m0 + 32; ++m) {
            int r = rows_s[m];
            float vv = b2f(*(const unsigned short*)((const char*)(Ain + m * 128) + ((2 * n) ^ ((m & 7) << 4))));
            if (r != cur) { atomicAdd(&agg[(size_t)cur * HD + n], s); s = 0.f; cur = r; }
            s += vv;
        }
        atomicAdd(&agg[(size_t)cur * HD + n], s);
    }

    // coord MLP layer 1 (A = EF)
    layer_gemm<4, 8>(Ain, 256, wp + OFF_WC1, bc1, acc, w, lane);
    store_tile<8>(T1, 256, acc, w, lane);
    __syncthreads();
    // coord MLP layer 2 (no bias, no relu) -> O22 f32
    layer_gemm<4, 2>(T1, 256, wp + OFF_WCL, (const float*)nullptr, acc, w, lane);
    float* O22 = (float*)(Ain + 16384);
    {
        const int rb = 16 * w + ((lane >> 4) << 2), cb = lane & 15;
#pragma unroll
        for (int nf = 0; nf < 2; ++nf)
#pragma unroll
            for (int r = 0; r < 4; ++r)
                O22[(rb + r) * 32 + nf * 16 + cb] = acc[nf][r];
    }
    __syncthreads();

    // ---- wind: segmented reduce, scaled by per-edge rad
    if (tid < 256) {
        const int c = tid & 31, q = tid >> 5;
        if (c < 22) {
            const bool isU = c < LVN;
            const int lvl = isU ? c : c - LVN;
            float* dst = isU ? aggu : aggv;
            const float* radp = isU ? radu_s : radv_s;
            const int m0 = q * 16;
            int cur = rows_s[m0]; float s = 0.f;
            for (int m = m0; m < m0 + 16; ++m) {
                int r = rows_s[m];
                float vv = O22[m * 32 + c] * radp[m];
                if (r != cur) { atomicAdd(&dst[(size_t)cur * LVN + lvl], s); s = 0.f; cur = r; }
                s += vv;
            }
            atomicAdd(&dst[(size_t)cur * LVN + lvl], s);
        }
    }
}

// ---------------- lat-band mean ----------------
__global__ __launch_bounds__(256)
void lat_kernel(const float* __restrict__ agg, float* __restrict__ lat)
{
    int t = blockIdx.x * 256 + threadIdx.x;
    if (t >= NLAT * HD) return;
    int i = t / HD, j = t % HD;
    float s = 0.f;
    for (int lon = 0; lon < NLON; ++lon)
        s += agg[((size_t)i * NLON + lon) * HD + j];
    lat[t] = s * (1.0f / NLON);
}

// ---------------- node kernel ----------------
__global__ __launch_bounds__(512, 1)
void node_mfma(const float* __restrict__ h, const float* __restrict__ lat,
               const float* __restrict__ bn1, const float* __restrict__ bn2,
               const short* __restrict__ wp, float* __restrict__ out)
{
    __shared__ short Ain[128 * 384];   // 96 KB, 768B rows
    __shared__ short T1[128 * 128];
    const int tid = threadIdx.x, lane = tid & 63, w = tid >> 6;
    const int n0 = blockIdx.x * 128;
    {
        const int m = tid >> 2, q = tid & 3;
        const int n = n0 + m;
        const bool valid = n < NN;
        const int li = (valid ? n : 0) / NLON;
        short* arow = Ain + m * 384;
        const int sw = (m & 7) << 4;
        const float* srcs[3];
        srcs[0] = h + (size_t)n * HD;
        srcs[1] = out + (size_t)n * HD;      // agg (this block's rows only)
        srcs[2] = lat + (size_t)li * HD;
#pragma unroll
        for (int p = 0; p < 3; ++p) {
            const float* sp = srcs[p] + q * 32;
            const int bb = p * 256 + q * 64;
#pragma unroll
            for (int k2 = 0; k2 < 4; ++k2) {
                short8 pk;
#pragma unroll
                for (int j = 0; j < 8; ++j)
                    pk[j] = valid ? (short)f2b(sp[8 * k2 + j]) : (short)0;
                *(short8*)((char*)arow + ((bb + 16 * k2) ^ sw)) = pk;
            }
        }
    }
    __syncthreads();
    f4 acc[8];
    layer_gemm<12, 8>(Ain, 768, wp + OFF_WN1, bn1, acc, w, lane);
    store_tile<8>(T1, 256, acc, w, lane);
    __syncthreads();
    layer_gemm<4, 8>(T1, 256, wp + OFF_WN2, bn2, acc, w, lane);
    const int rb = 16 * w + ((lane >> 4) << 2), cb = lane & 15;
#pragma unroll
    for (int nf = 0; nf < 8; ++nf)
#pragma unroll
        for (int r = 0; r < 4; ++r) {
            int gn = n0 + rb + r;
            if (gn < NN) {
                int colj = nf * 16 + cb;
                out[(size_t)gn * HD + colj] = acc[nf][r] + h[(size_t)gn * HD + colj];
            }
        }
}

// ---------------- wind finalize ----------------
__global__ __launch_bounds__(256)
void wind_final(float* __restrict__ aggu, float* __restrict__ aggv,
                const int* __restrict__ off)
{
    int t = blockIdx.x * 256 + threadIdx.x;
    if (t >= NN * LVN) return;
    int n = t / LVN;
    float c = fmaxf((float)(off[n + 1] - off[n]), 1.f);
    float xu = aggu[t] / c, xv = aggv[t] / c;
    aggu[t] = fminf(fmaxf(xu, -100.f), 100.f);
    aggv[t] = fminf(fmaxf(xv, -100.f), 100.f);
}

extern "C" void kernel_launch(void* const* d_in, const int* in_sizes, int n_in,
                              void* d_out, int out_size, void* d_ws, size_t ws_size,
                              hipStream_t stream)
{
    const float* h   = (const float*)d_in[0];
    const float* u   = (const float*)d_in[1];
    const float* v   = (const float*)d_in[2];
    const float* ea  = (const float*)d_in[3];
    const float* We1 = (const float*)d_in[4];
    const float* be1 = (const float*)d_in[5];
    const float* We2 = (const float*)d_in[6];
    const float* be2 = (const float*)d_in[7];
    const float* Wn1 = (const float*)d_in[8];
    const float* bn1 = (const float*)d_in[9];
    const float* Wn2 = (const float*)d_in[10];
    const float* bn2 = (const float*)d_in[11];
    const float* Wc1 = (const float*)d_in[12];
    const float* bc1 = (const float*)d_in[13];
    const float* Wcl = (const float*)d_in[14];
    const int*   eidx = (const int*)d_in[15];

    float* out  = (float*)d_out;
    float* agg  = out;                       // [NN,HD]: agg accum, then h_out
    float* aggu = out + (size_t)NN * HD;
    float* aggv = aggu + (size_t)NN * LVN;

    // workspace: wp (bf16 packed weights) overlaps cnt/cur (dead after CSR build)
    short* wp  = (short*)d_ws;                              // 143360 shorts = 286720 B
    int*   cnt = (int*)d_ws;                                // [NN]  (overlap, pre-prep only)
    int*   cur = cnt + NN;                                  // [NN]
    int*   off = (int*)((char*)d_ws + WP_SHORTS * 2);       // [NN+1]
    int*   csr = off + NN + 1;                              // [EE]
    float* lat = (float*)(csr + EE);                        // [NLAT*HD]

    hipMemsetAsync(d_out, 0, (size_t)out_size * sizeof(float), stream);
    hipMemsetAsync(d_ws, 0, (size_t)2 * NN * sizeof(int), stream);

    hist_kernel<<<EE / 256, 256, 0, stream>>>(eidx, cnt);
    scan_kernel<<<1, 1024, 0, stream>>>(cnt, off);
    scatter_kernel<<<EE / 256, 256, 0, stream>>>(eidx, off, cur, csr);
    prep_kernel<<<280, 64, 0, stream>>>(We1, We2, Wc1, Wcl, Wn1, Wn2, wp);

    edge_mfma<<<EE / 128, 512, 0, stream>>>(h, u, v, ea, be1, be2, bc1,
                                            wp, eidx, csr, agg, aggu, aggv);

    lat_kernel<<<(NLAT * HD + 255) / 256, 256, 0, stream>>>(agg, lat);

    node_mfma<<<(NN + 127) / 128, 512, 0, stream>>>(h, lat, bn1, bn2, wp, agg);

    wind_final<<<(NN * LVN + 255) / 256, 256, 0, stream>>>(aggu, aggv, off);
}

// Round 4
// 362.647 us; speedup vs baseline: 35.4324x; 1.5229x over previous
//
#include <hip/hip_runtime.h>
#include <math.h>

#define NN   29040
#define NLAT 121
#define NLON 240
#define HD   128
#define LVN  11
#define EE   464640

typedef __attribute__((ext_vector_type(8))) short short8;
typedef __attribute__((ext_vector_type(4))) float f4;

// packed-weight offsets (in shorts) inside wp buffer
#define OFF_WE1 0          // 10 kf x 8 nf  = 80 frags
#define OFF_WE2 40960      // 4 x 8 = 32
#define OFF_WC1 57344      // 4 x 8 = 32
#define OFF_WCL 73728      // 4 x 2 = 8
#define OFF_WN1 77824      // 12 x 8 = 96
#define OFF_WN2 126976     // 4 x 8 = 32
#define WP_SHORTS 143360

__device__ inline unsigned short f2b(float x) {
    union { float f; unsigned u; } v; v.f = x;
    unsigned r = v.u + 0x7FFFu + ((v.u >> 16) & 1u);
    return (unsigned short)(r >> 16);
}
__device__ inline float b2f(unsigned short b) {
    union { unsigned u; float f; } v; v.u = ((unsigned)b) << 16;
    return v.f;
}

// ---------------- CSR build ----------------
__global__ __launch_bounds__(256)
void hist_kernel(const int* __restrict__ eidx, int* __restrict__ cnt)
{
    int e = blockIdx.x * 256 + threadIdx.x;
    if (e < EE) atomicAdd(&cnt[eidx[e]], 1);
}

__global__ __launch_bounds__(1024)
void scan_kernel(const int* __restrict__ cnt, int* __restrict__ off)
{
    __shared__ int part[1024];
    const int tid = threadIdx.x;
    const int CH = 29;
    int lo = tid * CH, hi = min(lo + CH, NN);
    int s = 0;
    for (int i = lo; i < hi; ++i) s += cnt[i];
    part[tid] = s;
    __syncthreads();
    for (int d = 1; d < 1024; d <<= 1) {
        int vv = (tid >= d) ? part[tid - d] : 0;
        __syncthreads();
        part[tid] += vv;
        __syncthreads();
    }
    int run = (tid == 0) ? 0 : part[tid - 1];
    for (int i = lo; i < hi; ++i) { off[i] = run; run += cnt[i]; }
    if (tid == 1023) off[NN] = run;
}

__global__ __launch_bounds__(256)
void scatter_kernel(const int* __restrict__ eidx, const int* __restrict__ off,
                    int* __restrict__ cur, int* __restrict__ csr)
{
    int e = blockIdx.x * 256 + threadIdx.x;
    if (e >= EE) return;
    int row = eidx[e];
    int p = atomicAdd(&cur[row], 1);
    csr[off[row] + p] = e;
}

// ---------------- per-node precompute ----------------
__global__ __launch_bounds__(256)
void h_prep(const float* __restrict__ h, short* __restrict__ hb)
{
    int t = blockIdx.x * 256 + threadIdx.x;
    if (t < NN * HD) hb[t] = (short)f2b(h[t]);
}

// uvrec per node (36 floats): [0..10]=u/s, [11..21]=v/s, [22..32]=s, [33]=|u|, [34]=|v|, [35]=pad
__global__ __launch_bounds__(256)
void uv_prep(const float* __restrict__ u, const float* __restrict__ v,
             float* __restrict__ uvrec)
{
    int n = blockIdx.x * 256 + threadIdx.x;
    if (n >= NN) return;
    float* r = uvrec + (size_t)n * 36;
    float un = 0.f, vn = 0.f;
#pragma unroll
    for (int l = 0; l < LVN; ++l) {
        float uu = u[n * LVN + l], vv = v[n * LVN + l];
        float s = sqrtf(uu * uu + vv * vv);
        r[l]      = uu / s;
        r[11 + l] = vv / s;
        r[22 + l] = s;
        un += uu * uu; vn += vv * vv;
    }
    r[33] = sqrtf(un);
    r[34] = sqrtf(vn);
    r[35] = 0.f;
}

// ---------------- weight pack (same fragment order as round 3) ----------------
__global__ __launch_bounds__(64)
void prep_kernel(const float* __restrict__ We1, const float* __restrict__ We2,
                 const float* __restrict__ Wc1, const float* __restrict__ Wcl,
                 const float* __restrict__ Wn1, const float* __restrict__ Wn2,
                 short* __restrict__ wp)
{
    const int b = blockIdx.x, l = threadIdx.x;
    int kind, f, base;
    if (b < 80)       { kind = 0; f = b;       base = OFF_WE1; }
    else if (b < 112) { kind = 1; f = b - 80;  base = OFF_WE2; }
    else if (b < 144) { kind = 2; f = b - 112; base = OFF_WC1; }
    else if (b < 152) { kind = 3; f = b - 144; base = OFF_WCL; }
    else if (b < 248) { kind = 4; f = b - 152; base = OFF_WN1; }
    else              { kind = 5; f = b - 248; base = OFF_WN2; }
    const int nfw = (kind == 3) ? 2 : 8;
    const int kf = f / nfw, nf = f % nfw;
    short* dst = wp + base + (size_t)f * 512 + l * 8;
    for (int i = 0; i < 8; ++i) {
        int k = kf * 32 + ((l >> 4) << 3) + i;
        int n = nf * 16 + (l & 15);
        float val = 0.f;
        if (kind == 0) {
            int r = (k < 33) ? (256 + k) : (k == 33 ? 289 : (k < 64 ? -1 : k - 64));
            if (r >= 0) val = We1[r * HD + n];
        } else if (kind == 1) val = We2[k * HD + n];
        else if (kind == 2)  val = Wc1[k * HD + n];
        else if (kind == 3)  { if (n < 22) val = Wcl[k * 22 + n]; }
        else if (kind == 4)  val = Wn1[k * HD + n];
        else                 val = Wn2[k * HD + n];
        dst[i] = (short)f2b(val);
    }
}

// ---------------- GEMM helpers ----------------
// A in LDS, rows stride rs bytes, XOR-swizzled byte^((m&7)<<4)
template<int KF, int NF>
__device__ inline void layer_gemm(const short* At, int rs, const short* Wp,
                                  const float* bias, f4* acc, int w, int lane)
{
    const int m = 16 * w + (lane & 15);
    const char* arow = (const char*)At + m * rs;
    const int sw = (m & 7) << 4;
    const int kb = (lane >> 4) << 4;
#pragma unroll
    for (int nf = 0; nf < NF; ++nf) {
        float bv = bias ? bias[nf * 16 + (lane & 15)] : 0.f;
        acc[nf] = (f4){bv, bv, bv, bv};
    }
#pragma unroll
    for (int kf = 0; kf < KF; ++kf) {
        short8 a = *(const short8*)(arow + ((kf * 64 + kb) ^ sw));
        const short8* wr = (const short8*)(Wp + (size_t)kf * NF * 512) + lane;
#pragma unroll
        for (int nf = 0; nf < NF; ++nf) {
            short8 bfr = wr[nf * 64];
            acc[nf] = __builtin_amdgcn_mfma_f32_16x16x32_bf16(a, bfr, acc[nf], 0, 0, 0);
        }
    }
}

template<int NF>
__device__ inline void store_tile(short* tile, int rs, const f4* acc, int w, int lane)
{
    const int rb = 16 * w + ((lane >> 4) << 2);
    const int cb = (lane & 15) * 2;
#pragma unroll
    for (int nf = 0; nf < NF; ++nf)
#pragma unroll
        for (int r = 0; r < 4; ++r) {
            int row = rb + r;
            float vv = fmaxf(acc[nf][r], 0.f);
            *(short*)((char*)tile + row * rs + ((cb + nf * 32) ^ ((row & 7) << 4))) = (short)f2b(vv);
        }
}

// ---------------- edge kernel ----------------
__global__ __launch_bounds__(512, 4)
void edge_mfma(const short* __restrict__ hb, const float* __restrict__ uvrec,
               const float* __restrict__ ea,
               const float* __restrict__ be1, const float* __restrict__ be2,
               const float* __restrict__ bc1,
               const short* __restrict__ wp,
               const int* __restrict__ eidx, const int* __restrict__ csr,
               float* __restrict__ agg, float* __restrict__ aggu,
               float* __restrict__ aggv)
{
    __shared__ short Twd[128 * 64];    // 16 KB wd tile (128B rows, swizzled); later O22 f32
    __shared__ short T1[128 * 128];    // 32 KB (256B rows, swizzled)
    __shared__ int   rows_s[128];
    __shared__ int   cols_s[128];
    __shared__ float ea_s[128], radu_s[128], radv_s[128];

    const int tid = threadIdx.x, lane = tid & 63, w = tid >> 6;
    const int e0 = blockIdx.x * 128;

    if (tid < 128) {
        int e = csr[e0 + tid];
        rows_s[tid] = eidx[e];
        cols_s[tid] = eidx[EE + e];
        ea_s[tid]   = ea[e];
    }
    __syncthreads();

    // ---- wd tile build (wave-private rows: tid>>2 in [16w,16w+16)) ----
    {
        const int m = tid >> 2, q = tid & 3;
        const int row = rows_s[m], col = cols_s[m];
        char* arow = (char*)(Twd + m * 64);
        const int sw = (m & 7) << 4;
        // zero own 32B chunk of the 128B row (physical bytes, swizzle-agnostic)
        short8 z = {0, 0, 0, 0, 0, 0, 0, 0};
        *(short8*)(arow + q * 32) = z;
        *(short8*)(arow + q * 32 + 16) = z;
        const float* rc = uvrec + (size_t)col * 36;
        const float* rr = uvrec + (size_t)row * 36;
        for (int l = q; l < LVN; l += 4) {
            float rel = rc[l] * rr[l] + rc[11 + l] * rr[11 + l];
            *(short*)(arow + ((2 * l) ^ sw))        = (short)f2b(rel);
            *(short*)(arow + ((2 * (11 + l)) ^ sw)) = (short)f2b(rc[22 + l]);
            *(short*)(arow + ((2 * (22 + l)) ^ sw)) = (short)f2b(rr[22 + l]);
        }
        if (q == 0) { radu_s[m] = rc[33]; radv_s[m] = rc[34]; }
        if (q == 3) *(short*)(arow + ((2 * 33) ^ sw)) = (short)f2b(ea_s[m]);
    }

    const int mrow = 16 * w + (lane & 15);
    const int koff = 8 * (lane >> 4);
    const int sw   = (mrow & 7) << 4;
    const short* hr = hb + (size_t)rows_s[mrow] * HD + koff;
    const short* hc = hb + (size_t)cols_s[mrow] * HD + koff;
    const char*  awd = (const char*)(Twd + mrow * 64);

    f4 acc[8];
    // ---- edge MLP layer 1: bias init, wd(LDS) + h_row + h_col (direct global frags)
#pragma unroll
    for (int nf = 0; nf < 8; ++nf) {
        float bv = be1[nf * 16 + (lane & 15)];
        acc[nf] = (f4){bv, bv, bv, bv};
    }
    short8 ar[4], ac[4];
#pragma unroll
    for (int kf = 0; kf < 4; ++kf) {
        ar[kf] = *(const short8*)(hr + kf * 32);
        ac[kf] = *(const short8*)(hc + kf * 32);
    }
#pragma unroll
    for (int kf = 0; kf < 2; ++kf) {
        short8 a = *(const short8*)(awd + ((kf * 64 + 2 * koff) ^ sw));
        const short8* wr = (const short8*)(wp + OFF_WE1 + (size_t)kf * 8 * 512) + lane;
#pragma unroll
        for (int nf = 0; nf < 8; ++nf)
            acc[nf] = __builtin_amdgcn_mfma_f32_16x16x32_bf16(a, wr[nf * 64], acc[nf], 0, 0, 0);
    }
#pragma unroll
    for (int kf = 0; kf < 4; ++kf) {
        const short8* wr = (const short8*)(wp + OFF_WE1 + (size_t)(kf + 2) * 8 * 512) + lane;
#pragma unroll
        for (int nf = 0; nf < 8; ++nf)
            acc[nf] = __builtin_amdgcn_mfma_f32_16x16x32_bf16(ar[kf], wr[nf * 64], acc[nf], 0, 0, 0);
    }
#pragma unroll
    for (int kf = 0; kf < 4; ++kf) {
        const short8* wr = (const short8*)(wp + OFF_WE1 + (size_t)(kf + 6) * 8 * 512) + lane;
#pragma unroll
        for (int nf = 0; nf < 8; ++nf)
            acc[nf] = __builtin_amdgcn_mfma_f32_16x16x32_bf16(ac[kf], wr[nf * 64], acc[nf], 0, 0, 0);
    }
    store_tile<8>(T1, 256, acc, w, lane);       // Y1 (wave-private rows)

    // ---- edge MLP layer 2 -> EF (wave-private, no barrier) ----
    layer_gemm<4, 8>(T1, 256, wp + OFF_WE2, be2, acc, w, lane);
    store_tile<8>(T1, 256, acc, w, lane);       // EF over Y1 (private)

    // ---- coord MLP layer 1 (reads private EF rows) ----
    f4 accC[8];
    layer_gemm<4, 8>(T1, 256, wp + OFF_WC1, bc1, accC, w, lane);

    __syncthreads();
    // ---- agg: segmented reduce over sorted rows (cross-wave reads of EF) ----
    {
        const int n = tid & 127, q = tid >> 7;
        const int m0 = q * 32;
        int cur = rows_s[m0]; float s = 0.f;
        for (int m = m0; m < m0 + 32; ++m) {
            int r = rows_s[m];
            float vv = b2f(*(const unsigned short*)((const char*)(T1 + m * 128) + ((2 * n) ^ ((m & 7) << 4))));
            if (r != cur) { atomicAdd(&agg[(size_t)cur * HD + n], s); s = 0.f; cur = r; }
            s += vv;
        }
        atomicAdd(&agg[(size_t)cur * HD + n], s);
    }
    __syncthreads();

    // ---- coord layer C1 store + final layer (private) ----
    store_tile<8>(T1, 256, accC, w, lane);
    layer_gemm<4, 2>(T1, 256, wp + OFF_WCL, (const float*)nullptr, accC, w, lane);
    float* O22 = (float*)Twd;                   // 128x32 f32 = 16 KB (wd tile dead)
    {
        const int rb = 16 * w + ((lane >> 4) << 2), cb = lane & 15;
#pragma unroll
        for (int nf = 0; nf < 2; ++nf)
#pragma unroll
            for (int r = 0; r < 4; ++r)
                O22[(rb + r) * 32 + nf * 16 + cb] = accC[nf][r];
    }
    __syncthreads();

    // ---- wind: segmented reduce, scaled by per-edge (col-node) norms ----
    if (tid < 256) {
        const int c = tid & 31, q = tid >> 5;
        if (c < 22) {
            const bool isU = c < LVN;
            const int lvl = isU ? c : c - LVN;
            float* dst = isU ? aggu : aggv;
            const float* radp = isU ? radu_s : radv_s;
            const int m0 = q * 16;
            int cur = rows_s[m0]; float s = 0.f;
            for (int m = m0; m < m0 + 16; ++m) {
                int r = rows_s[m];
                float vv = O22[m * 32 + c] * radp[m];
                if (r != cur) { atomicAdd(&dst[(size_t)cur * LVN + lvl], s); s = 0.f; cur = r; }
                s += vv;
            }
            atomicAdd(&dst[(size_t)cur * LVN + lvl], s);
        }
    }
}

// ---------------- lat-band mean (writes bf16) ----------------
__global__ __launch_bounds__(256)
void lat_kernel(const float* __restrict__ agg, short* __restrict__ latb)
{
    __shared__ float part[256];
    const int i = blockIdx.x;                   // lat band
    const int tid = threadIdx.x;
    const int j = tid & 127, half = tid >> 7;
    float s = 0.f;
    for (int lon = half * 120; lon < (half + 1) * 120; ++lon)
        s += agg[((size_t)i * NLON + lon) * HD + j];
    part[tid] = s;
    __syncthreads();
    if (tid < 128)
        latb[(size_t)i * HD + tid] = (short)f2b((part[tid] + part[128 + tid]) * (1.0f / NLON));
}

// ---------------- node kernel (direct-reg A, zero barriers) ----------------
__global__ __launch_bounds__(512, 4)
void node_mfma(const short* __restrict__ hb, const float* __restrict__ h,
               const short* __restrict__ latb,
               const float* __restrict__ bn1, const float* __restrict__ bn2,
               const short* __restrict__ wp, float* __restrict__ out)
{
    __shared__ short T1[128 * 128];
    const int tid = threadIdx.x, lane = tid & 63, w = tid >> 6;
    const int n0 = blockIdx.x * 128;
    const int mrow = 16 * w + (lane & 15);
    const int koff = 8 * (lane >> 4);
    const int n = n0 + mrow;
    const int nc = (n < NN) ? n : (NN - 1);
    const short* hp = hb + (size_t)nc * HD + koff;
    const float* ap = out + (size_t)nc * HD + koff;   // agg lives in out region
    const short* lp = latb + (size_t)(nc / NLON) * HD + koff;

    f4 acc[8];
#pragma unroll
    for (int nf = 0; nf < 8; ++nf) {
        float bv = bn1[nf * 16 + (lane & 15)];
        acc[nf] = (f4){bv, bv, bv, bv};
    }
    // h part (kf 0..3), agg part (kf 4..7, f32->bf16 in reg), lat part (kf 8..11)
#pragma unroll
    for (int kf = 0; kf < 4; ++kf) {
        short8 a = *(const short8*)(hp + kf * 32);
        const short8* wr = (const short8*)(wp + OFF_WN1 + (size_t)kf * 8 * 512) + lane;
#pragma unroll
        for (int nf = 0; nf < 8; ++nf)
            acc[nf] = __builtin_amdgcn_mfma_f32_16x16x32_bf16(a, wr[nf * 64], acc[nf], 0, 0, 0);
    }
#pragma unroll
    for (int kf = 0; kf < 4; ++kf) {
        short8 a;
#pragma unroll
        for (int j = 0; j < 8; ++j) a[j] = (short)f2b(ap[kf * 32 + j]);
        const short8* wr = (const short8*)(wp + OFF_WN1 + (size_t)(kf + 4) * 8 * 512) + lane;
#pragma unroll
        for (int nf = 0; nf < 8; ++nf)
            acc[nf] = __builtin_amdgcn_mfma_f32_16x16x32_bf16(a, wr[nf * 64], acc[nf], 0, 0, 0);
    }
#pragma unroll
    for (int kf = 0; kf < 4; ++kf) {
        short8 a = *(const short8*)(lp + kf * 32);
        const short8* wr = (const short8*)(wp + OFF_WN1 + (size_t)(kf + 8) * 8 * 512) + lane;
#pragma unroll
        for (int nf = 0; nf < 8; ++nf)
            acc[nf] = __builtin_amdgcn_mfma_f32_16x16x32_bf16(a, wr[nf * 64], acc[nf], 0, 0, 0);
    }
    store_tile<8>(T1, 256, acc, w, lane);       // wave-private
    layer_gemm<4, 8>(T1, 256, wp + OFF_WN2, bn2, acc, w, lane);

    const int rb = 16 * w + ((lane >> 4) << 2), cb = lane & 15;
#pragma unroll
    for (int nf = 0; nf < 8; ++nf)
#pragma unroll
        for (int r = 0; r < 4; ++r) {
            int gn = n0 + rb + r;
            if (gn < NN) {
                int colj = nf * 16 + cb;
                out[(size_t)gn * HD + colj] = acc[nf][r] + h[(size_t)gn * HD + colj];
            }
        }
}

// ---------------- wind finalize ----------------
__global__ __launch_bounds__(256)
void wind_final(float* __restrict__ aggu, float* __restrict__ aggv,
                const int* __restrict__ off)
{
    int t = blockIdx.x * 256 + threadIdx.x;
    if (t >= NN * LVN) return;
    int n = t / LVN;
    float c = fmaxf((float)(off[n + 1] - off[n]), 1.f);
    float xu = aggu[t] / c, xv = aggv[t] / c;
    aggu[t] = fminf(fmaxf(xu, -100.f), 100.f);
    aggv[t] = fminf(fmaxf(xv, -100.f), 100.f);
}

extern "C" void kernel_launch(void* const* d_in, const int* in_sizes, int n_in,
                              void* d_out, int out_size, void* d_ws, size_t ws_size,
                              hipStream_t stream)
{
    const float* h   = (const float*)d_in[0];
    const float* u   = (const float*)d_in[1];
    const float* v   = (const float*)d_in[2];
    const float* ea  = (const float*)d_in[3];
    const float* We1 = (const float*)d_in[4];
    const float* be1 = (const float*)d_in[5];
    const float* We2 = (const float*)d_in[6];
    const float* be2 = (const float*)d_in[7];
    const float* Wn1 = (const float*)d_in[8];
    const float* bn1 = (const float*)d_in[9];
    const float* Wn2 = (const float*)d_in[10];
    const float* bn2 = (const float*)d_in[11];
    const float* Wc1 = (const float*)d_in[12];
    const float* bc1 = (const float*)d_in[13];
    const float* Wcl = (const float*)d_in[14];
    const int*   eidx = (const int*)d_in[15];

    float* out  = (float*)d_out;
    float* agg  = out;                       // [NN,HD]: agg accum, then h_out
    float* aggu = out + (size_t)NN * HD;
    float* aggv = aggu + (size_t)NN * LVN;

    // ---- workspace layout ----
    // [0, 286720):       wp (bf16 packed weights); overlapped by cnt/cur pre-prep
    // [286720, ...):     off[NN+1], csr[EE], hb, uvrec, latb
    short* wp  = (short*)d_ws;
    int*   cnt = (int*)d_ws;                         // [NN]   (dead after scatter)
    int*   cur = cnt + NN;                           // [NN]
    int*   off = (int*)((char*)d_ws + WP_SHORTS * 2);            // [NN+1]
    int*   csr = off + NN + 1;                                   // [EE]
    char*  p   = (char*)(csr + EE);
    p = (char*)(((size_t)p + 15) & ~(size_t)15);
    short* hb  = (short*)p;                  p += (size_t)NN * HD * 2;
    float* uvr = (float*)p;                  p += (size_t)NN * 36 * 4;
    short* latb = (short*)p;

    hipMemsetAsync(d_out, 0, (size_t)out_size * sizeof(float), stream);
    hipMemsetAsync(cnt, 0, (size_t)2 * NN * sizeof(int), stream);

    hist_kernel<<<EE / 256, 256, 0, stream>>>(eidx, cnt);
    scan_kernel<<<1, 1024, 0, stream>>>(cnt, off);
    scatter_kernel<<<EE / 256, 256, 0, stream>>>(eidx, off, cur, csr);
    prep_kernel<<<280, 64, 0, stream>>>(We1, We2, Wc1, Wcl, Wn1, Wn2, wp);
    h_prep<<<(NN * HD + 255) / 256, 256, 0, stream>>>(h, hb);
    uv_prep<<<(NN + 255) / 256, 256, 0, stream>>>(u, v, uvr);

    edge_mfma<<<EE / 128, 512, 0, stream>>>(hb, uvr, ea, be1, be2, bc1,
                                            wp, eidx, csr, agg, aggu, aggv);

    lat_kernel<<<NLAT, 256, 0, stream>>>(agg, latb);

    node_mfma<<<(NN + 127) / 128, 512, 0, stream>>>(hb, h, latb, bn1, bn2, wp, agg);

    wind_final<<<(NN * LVN + 255) / 256, 256, 0, stream>>>(aggu, aggv, off);
}